// Round 1
// baseline (97.555 us; speedup 1.0000x reference)
//
#include <hip/hip_runtime.h>

// GAPooling: out[b,n,c] = mean_k x[b, idx[b,n,k], c]
// B=16, N=4096, K=32, C=64, x fp32, idx int64-or-int32 (runtime-detected).

#define BB 16
#define NN 4096
#define KK 32
#define CC 64

// Detect whether idx is int64 (little-endian, values < 4096 => all high
// 32-bit words are zero) or int32. One block of 64 threads checks the first
// 64 odd 32-bit words; writes flag (1 = int64, 0 = int32) to workspace.
__global__ void detect_idx64_kernel(const int* __restrict__ w,
                                    int* __restrict__ flag) {
    int t = threadIdx.x;                 // 0..63
    int v = w[2 * t + 1];                // odd words
    unsigned long long nz = __ballot(v != 0);
    if (t == 0) *flag = (nz == 0ULL) ? 1 : 0;
}

// One wave (64 lanes) per output point (b,n).
// lane = ksub*16 + c4 : 16 lanes x float4 cover one 256B row of x,
// 4 k's processed per iteration; 8 iterations cover K=32.
__global__ __launch_bounds__(256)
void gapool_kernel(const float* __restrict__ x,
                   const int* __restrict__ idx32,
                   const int* __restrict__ flag,
                   float* __restrict__ out) {
    const int is64 = *flag;  // wave-uniform

    const int wave = (blockIdx.x * blockDim.x + threadIdx.x) >> 6;
    const int lane = threadIdx.x & 63;
    const int b = wave >> 12;          // / NN
    const int n = wave & (NN - 1);     // % NN
    const int ksub = lane >> 4;        // 0..3
    const int c4   = lane & 15;        // 0..15

    // Preload this point's 32 indices into lanes 0..31.
    const int ibase = (b * NN + n) * KK;
    int jv = 0;
    if (lane < KK) {
        jv = is64 ? idx32[2 * (ibase + lane)] : idx32[ibase + lane];
    }

    const float4* xb = (const float4*)x + (size_t)b * NN * (CC / 4);

    float4 acc = make_float4(0.f, 0.f, 0.f, 0.f);
#pragma unroll
    for (int ko = 0; ko < KK / 4; ++ko) {
        const int k = ko * 4 + ksub;
        const int j = __shfl(jv, k, 64);
        const float4 v = xb[j * (CC / 4) + c4];
        acc.x += v.x; acc.y += v.y; acc.z += v.z; acc.w += v.w;
    }

    // Sum across the 4 ksub groups (lane bits 4 and 5).
#pragma unroll
    for (int off = 16; off <= 32; off <<= 1) {
        acc.x += __shfl_xor(acc.x, off, 64);
        acc.y += __shfl_xor(acc.y, off, 64);
        acc.z += __shfl_xor(acc.z, off, 64);
        acc.w += __shfl_xor(acc.w, off, 64);
    }

    if (ksub == 0) {
        const float s = 1.0f / KK;
        float4 r = make_float4(acc.x * s, acc.y * s, acc.z * s, acc.w * s);
        ((float4*)out)[(size_t)(b * NN + n) * (CC / 4) + c4] = r;
    }
}

extern "C" void kernel_launch(void* const* d_in, const int* in_sizes, int n_in,
                              void* d_out, int out_size, void* d_ws, size_t ws_size,
                              hipStream_t stream) {
    const float* x     = (const float*)d_in[0];
    const int*   idx32 = (const int*)d_in[1];
    float*       out   = (float*)d_out;
    int*         flag  = (int*)d_ws;

    detect_idx64_kernel<<<1, 64, 0, stream>>>(idx32, flag);

    const int total_waves = BB * NN;          // 65536 points
    const int blocks = total_waves / 4;       // 4 waves per 256-thread block
    gapool_kernel<<<blocks, 256, 0, stream>>>(x, idx32, flag, out);
}

// Round 2
// 95.552 us; speedup vs baseline: 1.0210x; 1.0210x over previous
//
#include <hip/hip_runtime.h>

// GAPooling: out[b,n,c] = mean_k x[b, idx[b,n,k], c]
// B=16, N=4096, K=32, C=64, x fp32, idx int64-or-int32 (runtime-detected).
//
// One 64-thread block per point (b,n). blockIdx-derived idx addresses are
// wave-uniform -> compiler emits s_load for indices and scalar address math
// for row bases; each gather is a fully-coalesced 256B global_load_dword.

#define BB 16
#define NN 4096
#define KK 32
#define CC 64

__global__ void detect_idx64_kernel(const int* __restrict__ w,
                                    int* __restrict__ flag) {
    int t = threadIdx.x;                 // 0..63
    int v = w[2 * t + 1];                // odd words
    unsigned long long nz = __ballot(v != 0);
    if (t == 0) *flag = (nz == 0ULL) ? 1 : 0;
}

__global__ __launch_bounds__(64)
void gapool_kernel(const float* __restrict__ x,
                   const int* __restrict__ idx32,
                   const int* __restrict__ flag,
                   float* __restrict__ out) {
    const int point = blockIdx.x;        // uniform: b*NN + n
    const int b = point >> 12;           // / NN
    const int c = threadIdx.x;           // 0..63 = channel
    const int is64 = *flag;              // uniform

    const float* __restrict__ xb = x + (size_t)b * NN * CC;

    float acc = 0.0f;
    if (is64) {
        // int64 little-endian, values < 4096: low dword carries the value.
        const int* __restrict__ ip = idx32 + (size_t)point * KK * 2;
#pragma unroll
        for (int k = 0; k < KK; ++k) {
            const int j = ip[2 * k];             // uniform -> s_load
            acc += xb[(size_t)j * CC + c];       // saddr + lane offset
        }
    } else {
        const int* __restrict__ ip = idx32 + (size_t)point * KK;
#pragma unroll
        for (int k = 0; k < KK; ++k) {
            const int j = ip[k];                 // uniform -> s_load
            acc += xb[(size_t)j * CC + c];
        }
    }

    out[(size_t)point * CC + c] = acc * (1.0f / KK);
}

extern "C" void kernel_launch(void* const* d_in, const int* in_sizes, int n_in,
                              void* d_out, int out_size, void* d_ws, size_t ws_size,
                              hipStream_t stream) {
    const float* x     = (const float*)d_in[0];
    const int*   idx32 = (const int*)d_in[1];
    float*       out   = (float*)d_out;
    int*         flag  = (int*)d_ws;

    detect_idx64_kernel<<<1, 64, 0, stream>>>(idx32, flag);

    gapool_kernel<<<BB * NN, 64, 0, stream>>>(x, idx32, flag, out);
}

// Round 3
// 90.505 us; speedup vs baseline: 1.0779x; 1.0558x over previous
//
#include <hip/hip_runtime.h>

// GAPooling: out[b,n,c] = mean_k x[b, idx[b,n,k], c]
// B=16, N=4096, K=32, C=64, fp32. idx int64-or-int32 (runtime-detected).
//
// R3 structure: LDS-staged gather.
//   pack kernel:  idx -> uint16 (values < 4096) into d_ws (4 MiB).
//   main kernel:  grid = 16 batches x 16 channel-chunks (4 ch each).
//     Each block stages tile[n] = x[b][n][c0:c0+4] (64 KiB LDS), then each
//     lane gathers its own point's 32 neighbors via ds_read_b128 and
//     accumulates float4 in registers. No cross-lane reduction.
//   XCD swizzle: bid = chunk*16 + b -> bid%8 = b%8, so all chunks of a batch
//   share one XCD's L2 (x/idx16 resident; partial 16B output writes merge).

#define BB 16
#define NN 4096
#define KK 32
#define CC 64
#define CCH 4                 // channels per chunk
#define NCHUNK (CC / CCH)     // 16
#define THREADS 512

// Every wave computes the same flag: idx values < 4096, so if idx is int64
// (little-endian) all odd 32-bit words are zero.
__device__ __forceinline__ int detect_is64(const int* __restrict__ w) {
    int v = w[2 * (threadIdx.x & 63) + 1];
    return (__ballot(v != 0) == 0ULL) ? 1 : 0;
}

__global__ __launch_bounds__(256)
void pack_idx_kernel(const int* __restrict__ idx32,
                     ushort* __restrict__ out16) {
    const int is64 = detect_is64(idx32);
    const int tid = blockIdx.x * blockDim.x + threadIdx.x;
    const int stride = gridDim.x * blockDim.x;
    const int M = BB * NN * KK;           // 2,097,152 indices
    if (is64) {
        const int4* __restrict__ in = (const int4*)idx32;   // 2 int64 per int4
        uint* __restrict__ o = (uint*)out16;                // 2 u16 per uint
        for (int i = tid; i < M / 2; i += stride) {
            int4 v = in[i];
            o[i] = (uint)(v.x & 0xFFFF) | ((uint)(v.z & 0xFFFF) << 16);
        }
    } else {
        const int4* __restrict__ in = (const int4*)idx32;   // 4 int32 per int4
        uint2* __restrict__ o = (uint2*)out16;
        for (int i = tid; i < M / 4; i += stride) {
            int4 v = in[i];
            o[i] = make_uint2((uint)(v.x & 0xFFFF) | ((uint)(v.y & 0xFFFF) << 16),
                              (uint)(v.z & 0xFFFF) | ((uint)(v.w & 0xFFFF) << 16));
        }
    }
}

__global__ __launch_bounds__(THREADS)
void gapool_lds_kernel(const float* __restrict__ x,
                       const ushort* __restrict__ idx16,
                       float* __restrict__ out) {
    __shared__ float4 tile[NN];           // 64 KiB: x[b][n][c0:c0+4]

    const int bid = blockIdx.x;           // = chunk*16 + b
    const int b = bid & 15;
    const int chunk = bid >> 4;
    const int c0 = chunk * CCH;

    // ---- stage tile (coalesced-ish: lane n reads 16B of row n) ----
    const float4* __restrict__ xb4 =
        (const float4*)(x + ((size_t)b * NN) * CC + c0);   // stride CC/4=16 float4s
    for (int n = threadIdx.x; n < NN; n += THREADS) {
        tile[n] = xb4[(size_t)n * (CC / 4)];
    }
    __syncthreads();

    const int wave = threadIdx.x >> 6;
    const int lane = threadIdx.x & 63;
    const int nwaves = THREADS >> 6;

    const float s = 1.0f / KK;

    for (int pg = wave; pg < NN / 64; pg += nwaves) {
        const int n = pg * 64 + lane;                     // this lane's point
        const size_t row = ((size_t)b * NN + n) * KK;     // in u16 elements

        // Preload 32 packed u16 indices: 64B per lane, fully coalesced.
        const uint4* __restrict__ ip = (const uint4*)(idx16 + row);
        uint4 w0 = ip[0], w1 = ip[1], w2 = ip[2], w3 = ip[3];
        uint p[8] = {w0.x, w0.y, w0.z, w0.w, w1.x, w1.y, w1.z, w1.w};
        uint q[8] = {w2.x, w2.y, w2.z, w2.w, w3.x, w3.y, w3.z, w3.w};

        float4 acc0 = make_float4(0.f, 0.f, 0.f, 0.f);
        float4 acc1 = make_float4(0.f, 0.f, 0.f, 0.f);
#pragma unroll
        for (int i = 0; i < 8; ++i) {
            {
                float4 v = tile[p[i] & 0xFFFF];
                acc0.x += v.x; acc0.y += v.y; acc0.z += v.z; acc0.w += v.w;
            }
            {
                float4 v = tile[p[i] >> 16];
                acc1.x += v.x; acc1.y += v.y; acc1.z += v.z; acc1.w += v.w;
            }
            {
                float4 v = tile[q[i] & 0xFFFF];
                acc0.x += v.x; acc0.y += v.y; acc0.z += v.z; acc0.w += v.w;
            }
            {
                float4 v = tile[q[i] >> 16];
                acc1.x += v.x; acc1.y += v.y; acc1.z += v.z; acc1.w += v.w;
            }
        }

        float4 r = make_float4((acc0.x + acc1.x) * s, (acc0.y + acc1.y) * s,
                               (acc0.z + acc1.z) * s, (acc0.w + acc1.w) * s);
        *(float4*)(out + ((size_t)b * NN + n) * CC + c0) = r;
    }
}

extern "C" void kernel_launch(void* const* d_in, const int* in_sizes, int n_in,
                              void* d_out, int out_size, void* d_ws, size_t ws_size,
                              hipStream_t stream) {
    const float* x     = (const float*)d_in[0];
    const int*   idx32 = (const int*)d_in[1];
    float*       out   = (float*)d_out;
    ushort*      idx16 = (ushort*)d_ws;     // 4 MiB

    pack_idx_kernel<<<2048, 256, 0, stream>>>(idx32, idx16);

    gapool_lds_kernel<<<BB * NCHUNK, THREADS, 0, stream>>>(x, idx16, out);
}